// Round 9
// baseline (14929.427 us; speedup 1.0000x reference)
//
#include <hip/hip_runtime.h>
#include <hip/hip_bf16.h>

#define DI __device__ __forceinline__

DI float sgnf(float v) { return (v > 0.f) ? 1.f : ((v < 0.f) ? -1.f : 0.f); }

// Block-wide per-channel stats in FP64. All 256 threads must reach this.
DI void blockStatsD(double v, double* __restrict__ stats, int co, int C)
{
    double s = v, q = v * v;
#pragma unroll
    for (int o = 32; o; o >>= 1) { s += __shfl_down(s, o, 64); q += __shfl_down(q, o, 64); }
    __shared__ double ls[4], lq[4];
    int lane = threadIdx.x & 63, wid = threadIdx.x >> 6;
    if (lane == 0) { ls[wid] = s; lq[wid] = q; }
    __syncthreads();
    if (threadIdx.x == 0) {
        atomicAdd(&stats[co],     ls[0] + ls[1] + ls[2] + ls[3]);
        atomicAdd(&stats[C + co], lq[0] + lq[1] + lq[2] + lq[3]);
    }
}

// ---------------------------------------------------------------------------
// Layer 0: conv3x3 on fp32 input (Cin=3, 32x32) in FP64 (continuous values —
// the only precision-critical sign boundary). Bias omitted (cancels in BN).
DI double conv0_acc(const float* __restrict__ x, const double* wl, int idx)
{
    const int n = idx >> 10, hw = idx & 1023, y = hw >> 5, xx = hw & 31;
    const bool ym = y > 0, yp = y < 31, xm = xx > 0, xp = xx < 31;
    const float* ip = x + ((size_t)n * 3 << 10) + hw;
    double acc = 0.0;
#pragma unroll
    for (int ci = 0; ci < 3; ++ci, ip += 1024) {
        const double* wp = wl + ci * 9;
        if (ym) {
            if (xm) acc += (double)ip[-33] * wp[0];
            acc += (double)ip[-32] * wp[1];
            if (xp) acc += (double)ip[-31] * wp[2];
        }
        if (xm) acc += (double)ip[-1] * wp[3];
        acc += (double)ip[0] * wp[4];
        if (xp) acc += (double)ip[1] * wp[5];
        if (yp) {
            if (xm) acc += (double)ip[31] * wp[6];
            acc += (double)ip[32] * wp[7];
            if (xp) acc += (double)ip[33] * wp[8];
        }
    }
    return acc;
}

__global__ __launch_bounds__(256) void conv0_stats_k(
    const float* __restrict__ x, const float* __restrict__ w,
    double* __restrict__ stats)
{
    __shared__ double wl[27];
    const int co = blockIdx.y;
    if (threadIdx.x < 27) wl[threadIdx.x] = (double)sgnf(w[co * 27 + threadIdx.x]);
    __syncthreads();
    const int idx = blockIdx.x * 256 + threadIdx.x;   // over N*1024 = 131072
    double acc = conv0_acc(x, wl, idx);
    blockStatsD(acc, stats, co, 128);
}

__global__ __launch_bounds__(256) void conv0_bn_k(
    const float* __restrict__ x, const float* __restrict__ w,
    const double* __restrict__ stats,
    const float* __restrict__ g, const float* __restrict__ be,
    unsigned char* __restrict__ bin)
{
    __shared__ double wl[27];
    const int co = blockIdx.y;
    if (threadIdx.x < 27) wl[threadIdx.x] = (double)sgnf(w[co * 27 + threadIdx.x]);
    __syncthreads();
    const int idx = blockIdx.x * 256 + threadIdx.x;
    double acc = conv0_acc(x, wl, idx);
    const double inv = 1.0 / 131072.0;
    double m = stats[co] * inv;
    double v = stats[128 + co] * inv - m * m;
    double y = (acc - m) * (1.0 / sqrt(v + 1e-5)) * (double)g[co] + (double)be[co];
    const int n = idx >> 10, hw = idx & 1023;
    bin[((size_t)(n * 128 + co) << 10) + hw] = (y > 0.0) ? 1 : 0;
}

// ---------------------------------------------------------------------------
// conv3x3 (no pool), u8 {0,1} input, sign weights. Sums are exact integers in
// fp32. Bias omitted (cancels in BN). FP64 stats fused.
__global__ __launch_bounds__(256) void convs_k(
    const unsigned char* __restrict__ in, const float* __restrict__ w,
    float* __restrict__ out, double* __restrict__ stats,
    int Cin, int Cout, int logW, int logHW)
{
    __shared__ float wl[512 * 9];
    const int co = blockIdx.y;
    const int cw = Cin * 9;
    for (int i = threadIdx.x; i < cw; i += 256) wl[i] = sgnf(w[(size_t)co * cw + i]);
    __syncthreads();

    const int idx = blockIdx.x * 256 + threadIdx.x;   // over N<<logHW
    const int HW = 1 << logHW, W = 1 << logW, H = HW >> logW;
    const int n = idx >> logHW, hw = idx & (HW - 1);
    const int y = hw >> logW, xx = hw & (W - 1);
    const bool ym = y > 0, yp = y < H - 1, xm = xx > 0, xp = xx < W - 1;
    const unsigned char* ip = in + ((size_t)n * Cin << logHW) + hw;
    float acc = 0.f;
    const float* wp = wl;
    for (int ci = 0; ci < Cin; ++ci, ip += HW, wp += 9) {
        if (ym) {
            const unsigned char* r = ip - W;
            if (xm) acc += (float)r[-1] * wp[0];
            acc += (float)r[0] * wp[1];
            if (xp) acc += (float)r[1] * wp[2];
        }
        if (xm) acc += (float)ip[-1] * wp[3];
        acc += (float)ip[0] * wp[4];
        if (xp) acc += (float)ip[1] * wp[5];
        if (yp) {
            const unsigned char* r = ip + W;
            if (xm) acc += (float)r[-1] * wp[6];
            acc += (float)r[0] * wp[7];
            if (xp) acc += (float)r[1] * wp[8];
        }
    }
    out[((size_t)(n * Cout + co) << logHW) + hw] = acc;
    blockStatsD((double)acc, stats, co, Cout);
}

// ---------------------------------------------------------------------------
// conv3x3 + 2x2/2 maxpool fused, u8 input, exact-integer sums, FP64 stats.
__global__ __launch_bounds__(256) void convp_k(
    const unsigned char* __restrict__ in, const float* __restrict__ w,
    float* __restrict__ out, double* __restrict__ stats,
    int Cin, int Cout, int logWo, int logHWo)
{
    __shared__ float wl[512 * 9];
    const int co = blockIdx.y;
    const int cw = Cin * 9;
    for (int i = threadIdx.x; i < cw; i += 256) wl[i] = sgnf(w[(size_t)co * cw + i]);
    __syncthreads();

    const int idx = blockIdx.x * 256 + threadIdx.x;   // over N<<logHWo
    const int HWo = 1 << logHWo, Wo = 1 << logWo, Ho = HWo >> logWo;
    const int n = idx >> logHWo, hw = idx & (HWo - 1);
    const int yo = hw >> logWo, xo = hw & (Wo - 1);
    const int Wi = Wo << 1, Hi = Ho << 1, HWi = HWo << 2;
    const int yi0 = 2 * yo - 1, xi0 = 2 * xo - 1;
    const unsigned char* base = in + (size_t)(n * Cin) * HWi;
    float a00 = 0.f, a01 = 0.f, a10 = 0.f, a11 = 0.f;
    const float* wp = wl;
    for (int ci = 0; ci < Cin; ++ci, base += HWi, wp += 9) {
        float p[4][4];
#pragma unroll
        for (int r = 0; r < 4; ++r) {
            const int yi = yi0 + r;
            const bool yv = (unsigned)yi < (unsigned)Hi;
            const unsigned char* row = base + yi * Wi;
#pragma unroll
            for (int c = 0; c < 4; ++c) {
                const int xi = xi0 + c;
                p[r][c] = (yv && (unsigned)xi < (unsigned)Wi) ? (float)row[xi] : 0.f;
            }
        }
#pragma unroll
        for (int dy = 0; dy < 3; ++dy)
#pragma unroll
            for (int dx = 0; dx < 3; ++dx) {
                const float wv = wp[dy * 3 + dx];
                a00 += p[dy][dx] * wv;     a01 += p[dy][dx + 1] * wv;
                a10 += p[dy + 1][dx] * wv; a11 += p[dy + 1][dx + 1] * wv;
            }
    }
    const float m = fmaxf(fmaxf(a00, a01), fmaxf(a10, a11));
    out[((size_t)(n * Cout + co) << logHWo) + hw] = m;
    blockStatsD((double)m, stats, co, Cout);
}

// ---------------------------------------------------------------------------
// BN (FP64 stats & apply) + relu + sign -> u8 {0,1}. C power of two.
__global__ __launch_bounds__(256) void bn_sign_k(
    const float* __restrict__ in, const double* __restrict__ stats,
    const float* __restrict__ g, const float* __restrict__ be,
    unsigned char* __restrict__ out, int C, int logHW, double invcnt)
{
    const int idx = blockIdx.x * 256 + threadIdx.x;
    const int c = (idx >> logHW) & (C - 1);
    double m = stats[c] * invcnt;
    double v = stats[C + c] * invcnt - m * m;
    double y = ((double)in[idx] - m) * (1.0 / sqrt(v + 1e-5)) * (double)g[c] + (double)be[c];
    out[idx] = (y > 0.0) ? 1 : 0;
}

// ---------------------------------------------------------------------------
// FC: out[n,o] = sum_k a_u8[n,k] * sgn(w[o,k]) — exact integers, no bias.
__global__ __launch_bounds__(256) void fcbin_k(
    const unsigned char* __restrict__ a, const float* __restrict__ w,
    float* __restrict__ out, int N, int K, int O)
{
    __shared__ float As[16][17], Ws[16][17];
    const int tx = threadIdx.x & 15, ty = threadIdx.x >> 4;
    const int o0 = blockIdx.x * 16, n0 = blockIdx.y * 16;
    float acc = 0.f;
    for (int k0 = 0; k0 < K; k0 += 16) {
        As[ty][tx] = (float)a[(size_t)(n0 + ty) * K + k0 + tx];
        Ws[ty][tx] = sgnf(w[(size_t)(o0 + ty) * K + k0 + tx]);
        __syncthreads();
#pragma unroll
        for (int k = 0; k < 16; ++k) acc += As[ty][k] * Ws[tx][k];
        __syncthreads();
    }
    out[(size_t)(n0 + ty) * O + o0 + tx] = acc;
}

// per-feature FP64 stats over batch. One thread per feature, deterministic.
__global__ __launch_bounds__(256) void stats1d_k(
    const float* __restrict__ x, double* __restrict__ stats, int F, int N)
{
    const int f = blockIdx.x * 256 + threadIdx.x;
    if (f >= F) return;
    double s = 0.0, q = 0.0;
    for (int n = 0; n < N; ++n) { double v = (double)x[(size_t)n * F + f]; s += v; q += v * v; }
    stats[f] = s; stats[F + f] = q;
}

__global__ __launch_bounds__(256) void bn1d_sign_k(
    const float* __restrict__ in, const double* __restrict__ stats,
    const float* __restrict__ g, const float* __restrict__ be,
    unsigned char* __restrict__ out, int F, double invcnt)
{
    const int idx = blockIdx.x * 256 + threadIdx.x;
    const int f = idx & (F - 1);
    double m = stats[f] * invcnt;
    double v = stats[F + f] * invcnt - m * m;
    double y = ((double)in[idx] - m) * (1.0 / sqrt(v + 1e-5)) * (double)g[f] + (double)be[f];
    out[idx] = (y > 0.0) ? 1 : 0;
}

__global__ __launch_bounds__(256) void bn1d_relu_k(
    const float* __restrict__ in, const double* __restrict__ stats,
    const float* __restrict__ g, const float* __restrict__ be,
    float* __restrict__ out, int F, double invcnt)
{
    const int idx = blockIdx.x * 256 + threadIdx.x;
    const int f = idx & (F - 1);
    double m = stats[f] * invcnt;
    double v = stats[F + f] * invcnt - m * m;
    double y = ((double)in[idx] - m) * (1.0 / sqrt(v + 1e-5)) * (double)g[f] + (double)be[f];
    out[idx] = (float)fmax(y, 0.0);
}

// fc8 (10 outputs, raw fp32 weights, +b8) + log_softmax in FP64 -> fp32 out.
__global__ __launch_bounds__(256) void fc8_k(
    const float* __restrict__ a, const float* __restrict__ w,
    const float* __restrict__ b, float* __restrict__ out, int K)
{
    const int n = blockIdx.x;
    double acc[10];
#pragma unroll
    for (int o = 0; o < 10; ++o) acc[o] = 0.0;
    for (int k = threadIdx.x; k < K; k += 256) {
        double av = (double)a[(size_t)n * K + k];
#pragma unroll
        for (int o = 0; o < 10; ++o) acc[o] += av * (double)w[(size_t)o * K + k];
    }
    __shared__ double part[10 * 4];
    __shared__ double zs[10];
    const int lane = threadIdx.x & 63, wid = threadIdx.x >> 6;
#pragma unroll
    for (int o = 0; o < 10; ++o) {
        double v = acc[o];
#pragma unroll
        for (int s = 32; s; s >>= 1) v += __shfl_down(v, s, 64);
        if (lane == 0) part[o * 4 + wid] = v;
    }
    __syncthreads();
    if (threadIdx.x < 10) {
        int o = threadIdx.x;
        zs[o] = part[o * 4] + part[o * 4 + 1] + part[o * 4 + 2] + part[o * 4 + 3] + (double)b[o];
    }
    __syncthreads();
    if (threadIdx.x == 0) {
        double mx = zs[0];
#pragma unroll
        for (int o = 1; o < 10; ++o) mx = fmax(mx, zs[o]);
        double se = 0.0;
#pragma unroll
        for (int o = 0; o < 10; ++o) se += exp(zs[o] - mx);
        double ls = log(se);
#pragma unroll
        for (int o = 0; o < 10; ++o) out[n * 10 + o] = (float)(zs[o] - mx - ls);
    }
}

// ---------------------------------------------------------------------------
extern "C" void kernel_launch(void* const* d_in, const int* in_sizes, int n_in,
                              void* d_out, int out_size, void* d_ws, size_t ws_size,
                              hipStream_t stream)
{
    // Inputs fp32 (npz size proves it); OUTPUT fp32 (out_npz 4.7KB ≈ 1280*4B
    // deflated; rounds 1-4's sane absmax under fp32-reads excludes bf16-out).
    const float* x;
    const float *W[9], *Bb[9], *G[8], *Be[8];
    if (in_sizes[0] == 393216) {
        x = (const float*)d_in[0];
        for (int i = 0; i < 6; ++i) {
            W[i]  = (const float*)d_in[1 + 4 * i];
            Bb[i] = (const float*)d_in[2 + 4 * i];
            G[i]  = (const float*)d_in[3 + 4 * i];
            Be[i] = (const float*)d_in[4 + 4 * i];
        }
        W[6] = (const float*)d_in[25]; Bb[6] = (const float*)d_in[26];
        G[6] = (const float*)d_in[27]; Be[6] = (const float*)d_in[28];
        W[7] = (const float*)d_in[29]; Bb[7] = (const float*)d_in[30];
        G[7] = (const float*)d_in[31]; Be[7] = (const float*)d_in[32];
        W[8] = (const float*)d_in[33]; Bb[8] = (const float*)d_in[34];
    } else {
        for (int i = 0; i < 9; ++i) Bb[i] = (const float*)d_in[i];
        for (int i = 0; i < 8; ++i) Be[i] = (const float*)d_in[9 + i];
        for (int i = 0; i < 8; ++i) G[i]  = (const float*)d_in[17 + i];
        for (int i = 0; i < 9; ++i) W[i]  = (const float*)d_in[25 + i];
        x = (const float*)d_in[34];
    }

    // Workspace layout (55 MiB):
    char* ws = (char*)d_ws;
    double* dstats = (double*)ws;                                // 16 KiB max
    float* convb = (float*)(ws + (1ull << 20));                  // 32 MiB max
    unsigned char* binA = (unsigned char*)(ws + (33ull << 20));  // 16 MiB max
    unsigned char* binB = (unsigned char*)(ws + (49ull << 20));  //  4 MiB max
    float* fcO   = (float*)(ws + (53ull << 20));                 // 512 KiB
    float* fcA   = (float*)(ws + (54ull << 20));                 // 512 KiB
    float* out = (float*)d_out;
    const int N = 128;

    auto mst = [&](int C) { hipMemsetAsync(dstats, 0, 2 * C * sizeof(double), stream); };

    // L0 (fp64): stats pass, then bn+sign -> binA [128,128,32,32] u8
    mst(128);
    hipLaunchKernelGGL(conv0_stats_k, dim3(512, 128), 256, 0, stream, x, W[0], dstats);
    hipLaunchKernelGGL(conv0_bn_k, dim3(512, 128), 256, 0, stream,
                       x, W[0], dstats, G[0], Be[0], binA);
    // L1: conv+pool(binA) -> convb [128,128,16,16]; bn+sign -> binB
    mst(128);
    hipLaunchKernelGGL(convp_k, dim3(128, 128), 256, 0, stream,
                       binA, W[1], convb, dstats, 128, 128, 4, 8);
    hipLaunchKernelGGL(bn_sign_k, dim3((N * 128 << 8) / 256), 256, 0, stream,
                       convb, dstats, G[1], Be[1], binB, 128, 8, 1.0 / (N << 8));
    // L2: conv(binB) -> convb [128,256,16,16]; bn+sign -> binA
    mst(256);
    hipLaunchKernelGGL(convs_k, dim3(128, 256), 256, 0, stream,
                       binB, W[2], convb, dstats, 128, 256, 4, 8);
    hipLaunchKernelGGL(bn_sign_k, dim3((N * 256 << 8) / 256), 256, 0, stream,
                       convb, dstats, G[2], Be[2], binA, 256, 8, 1.0 / (N << 8));
    // L3: conv+pool(binA) -> convb [128,256,8,8]; bn+sign -> binB
    mst(256);
    hipLaunchKernelGGL(convp_k, dim3(32, 256), 256, 0, stream,
                       binA, W[3], convb, dstats, 256, 256, 3, 6);
    hipLaunchKernelGGL(bn_sign_k, dim3((N * 256 << 6) / 256), 256, 0, stream,
                       convb, dstats, G[3], Be[3], binB, 256, 6, 1.0 / (N << 6));
    // L4: conv(binB) -> convb [128,512,8,8]; bn+sign -> binA
    mst(512);
    hipLaunchKernelGGL(convs_k, dim3(32, 512), 256, 0, stream,
                       binB, W[4], convb, dstats, 256, 512, 3, 6);
    hipLaunchKernelGGL(bn_sign_k, dim3((N * 512 << 6) / 256), 256, 0, stream,
                       convb, dstats, G[4], Be[4], binA, 512, 6, 1.0 / (N << 6));
    // L5: conv+pool(binA) -> convb [128,512,4,4]; bn+sign -> binB [128,8192]u8
    mst(512);
    hipLaunchKernelGGL(convp_k, dim3(8, 512), 256, 0, stream,
                       binA, W[5], convb, dstats, 512, 512, 2, 4);
    hipLaunchKernelGGL(bn_sign_k, dim3((N * 512 << 4) / 256), 256, 0, stream,
                       convb, dstats, G[5], Be[5], binB, 512, 4, 1.0 / (N << 4));

    // fc6: integers -> fcO; fp64 stats; bn1d+sign -> binA [128,1024]u8
    hipLaunchKernelGGL(fcbin_k, dim3(64, 8), 256, 0, stream, binB, W[6], fcO, N, 8192, 1024);
    hipLaunchKernelGGL(stats1d_k, dim3(4), 256, 0, stream, fcO, dstats, 1024, N);
    hipLaunchKernelGGL(bn1d_sign_k, dim3(N * 1024 / 256), 256, 0, stream,
                       fcO, dstats, G[6], Be[6], binA, 1024, 1.0 / N);
    // fc7: -> fcO; bn1d+relu -> fcA (fp32)
    hipLaunchKernelGGL(fcbin_k, dim3(64, 8), 256, 0, stream, binA, W[7], fcO, N, 1024, 1024);
    hipLaunchKernelGGL(stats1d_k, dim3(4), 256, 0, stream, fcO, dstats, 1024, N);
    hipLaunchKernelGGL(bn1d_relu_k, dim3(N * 1024 / 256), 256, 0, stream,
                       fcO, dstats, G[7], Be[7], fcA, 1024, 1.0 / N);
    // fc8 + log_softmax (fp64) -> d_out [128,10] fp32
    hipLaunchKernelGGL(fc8_k, dim3(N), 256, 0, stream, fcA, W[8], Bb[8], out, 1024);
}